// Round 16
// baseline (118.741 us; speedup 1.0000x reference)
//
#include <hip/hip_runtime.h>
#include <algorithm>
#include <cstdint>

// PRNG: partitionable threefry, 32-bit combine = o0 ^ o1  [VERIFIED R4: absmax=0]
// Ledger: R8 gl2lds NEUTRAL; R9 fused-map -9us (device fence); R11 occupancy
// NEUTRAL; R12 T14 split NEUTRAL; R13/R14 reg-accum colsum -16us; R15 coalesced
// 2-stage colreduce -5.4us WIN (110.4). R16: direct-gather — no LDS, no barriers;
// per-thread index quads in registers; scattered reads served by L1/L2 (5.5KB
// window, full reuse); coalesced NT float4 stores.

constexpr int W_ = 690;
constexpr int NSEG_ = 2 * W_ + 1;   // 1381 segments
constexpr int NCUTS_ = 2 * W_ + 2;  // 1382 cut points
constexpr int TR4_ = 4;             // rows per colsum tile
constexpr int TFLT_ = TR4_ * W_;    // 2760 floats = 11040 B (16B-aligned tiles)
constexpr int TF4_ = TFLT_ / 4;     // 690 float4 per tile
constexpr int GFLT_ = 2 * W_;       // 1380 floats per gather window
constexpr int GF4_ = GFLT_ / 4;     // 345 float4 per window

typedef float v4f_ __attribute__((ext_vector_type(4)));

struct PermArg { unsigned short p[NSEG_]; }; // 2762 B kernarg, values < 1381

// ---------------- host-side threefry2x32 (exact JAX semantics) ----------------
static inline uint32_t rotl32_(uint32_t x, int d) { return (x << d) | (x >> (32 - d)); }

static void tf2x32(uint32_t k0, uint32_t k1, uint32_t x0, uint32_t x1,
                   uint32_t& o0, uint32_t& o1) {
  const uint32_t ks2 = k0 ^ k1 ^ 0x1BD11BDAu;
  x0 += k0; x1 += k1;
  const int RA[4] = {13, 15, 26, 6}, RB[4] = {17, 29, 16, 24};
#define FOUR_(R) for (int i_ = 0; i_ < 4; ++i_) { x0 += x1; x1 = rotl32_(x1, R[i_]); x1 ^= x0; }
  FOUR_(RA) x0 += k1;  x1 += ks2 + 1u;
  FOUR_(RB) x0 += ks2; x1 += k0 + 2u;
  FOUR_(RA) x0 += k0;  x1 += k1 + 3u;
  FOUR_(RB) x0 += k1;  x1 += ks2 + 4u;
  FOUR_(RA) x0 += ks2; x1 += k0 + 5u;
#undef FOUR_
  o0 = x0; o1 = x1;
}

// perm = argsort(uniform(key(42), (1381,))) — pure function of constants.
static void compute_perm(unsigned short* perm) {
  uint32_t uk[NSEG_];
  for (int i = 0; i < NSEG_; ++i) {
    uint32_t o0, o1;
    tf2x32(0u, 42u, 0u, (uint32_t)i, o0, o1); // u64 count i: hi=0 -> x0, lo=i -> x1
    uk[i] = (o0 ^ o1) >> 9; // partitionable bit_width==32: bits1 ^ bits2
  }
  int idx[NSEG_];
  for (int i = 0; i < NSEG_; ++i) idx[i] = i;
  std::stable_sort(idx, idx + NSEG_, [&](int a, int b) { return uk[a] < uk[b]; });
  for (int k = 0; k < NSEG_; ++k) perm[k] = (unsigned short)idx[k];
}

// ---------------- pass 1: double-buffered reg-staged LDS colsum (R10 verbatim) ----------------
__global__ __launch_bounds__(256) void k_colsum(const float* __restrict__ img,
                                                double* __restrict__ partial,
                                                int ntiles, int rows) {
  __shared__ float buf[2][TFLT_]; // 2 x 11040 B
  const int t = threadIdx.x;
  double a0 = 0.0, a1 = 0.0, a2 = 0.0;

  auto stage = [&](float* bp, int g) {
    const int nr = min(TR4_, rows - g * TR4_);
    if (nr == TR4_) {
      const v4f_* b4 = (const v4f_*)(img + (size_t)g * TFLT_); // 11040B*g: 16B aligned
      v4f_* t4 = (v4f_*)bp;
      for (int i = t; i < TF4_; i += 256) t4[i] = b4[i];
    } else {
      const int nflt = nr * W_;
      const float* b = img + (size_t)g * TFLT_;
      for (int i = t; i < nflt; i += 256) bp[i] = b[i];
    }
  };

  int g = blockIdx.x;
  int phase = 0;
  if (g < ntiles) stage(buf[0], g);
  for (; g < ntiles; g += gridDim.x) {
    __syncthreads(); // buf[phase] staged; prev accumulate of buf[phase^1] done
    const int gn = g + gridDim.x;
    if (gn < ntiles) stage(buf[phase ^ 1], gn); // prefetch next while we accumulate
    const int nr = min(TR4_, rows - g * TR4_);
    const float* bp = buf[phase];
    for (int r = 0; r < nr; ++r) {
      const float* row = bp + r * W_;
      a0 += (double)row[t];
      a1 += (double)row[t + 256];          // t+256 <= 511 < 690 always
      if (t + 512 < W_) a2 += (double)row[t + 512];
    }
    phase ^= 1;
  }
  double* o = partial + (size_t)blockIdx.x * W_;
  o[t] = a0;
  o[t + 256] = a1;
  if (t + 512 < W_) o[t + 512] = a2;
}

// ---------------- pass 1b: coalesced 2-stage reduction (R15 verbatim) ----------------
__global__ __launch_bounds__(256) void k_colreduce(const double* __restrict__ partial,
                                                   double* __restrict__ stage2, int nblk) {
  const int j = blockIdx.x >> 3;   // col chunk 0..10
  const int k = blockIdx.x & 7;    // b chunk 0..7
  const int t = threadIdx.x;
  const int c = j * 64 + (t & 63); // column
  const int wv = t >> 6;           // wave 0..3
  const bool ok = (c < W_);
  __shared__ double red[4][64];

  const int nsub = (nblk + 31) / 32;
  const int b0 = (k * 4 + wv) * nsub;
  const int b1 = min(b0 + nsub, nblk);
  double s0 = 0.0, s1 = 0.0, s2 = 0.0, s3 = 0.0;
  int b = b0;
  if (ok) {
    for (; b + 3 < b1; b += 4) { // 4 independent chains -> 4 loads in flight
      const double* p = partial + (size_t)b * W_ + c;
      s0 += p[0];
      s1 += p[(size_t)1 * W_];
      s2 += p[(size_t)2 * W_];
      s3 += p[(size_t)3 * W_];
    }
    for (; b < b1; ++b) s0 += partial[(size_t)b * W_ + c];
  }
  red[wv][t & 63] = (s0 + s1) + (s2 + s3);
  __syncthreads();
  if (wv == 0) {
    const int l = t & 63;
    const double tot = (red[0][l] + red[1][l]) + (red[2][l] + red[3][l]);
    if (ok) stage2[(size_t)k * W_ + c] = tot;
  }
}

// ---------------- hierarchical inclusive scan: 2 barriers, deterministic ----------------
template <int N>
__device__ inline void scan_fast(double* sa, int t, double* wtmp) {
  constexpr int C = (N + 255) / 256;
  double loc[C];
  const int base = t * C;
  double run = 0.0;
#pragma unroll
  for (int j = 0; j < C; ++j) {
    const int i = base + j;
    const double v = (i < N) ? sa[i] : 0.0;
    run += v;
    loc[j] = run;
  }
  const int lane = t & 63, wid = t >> 6;
  double x = run;
#pragma unroll
  for (int off = 1; off < 64; off <<= 1) {
    const double y = __shfl_up(x, off);
    if (lane >= off) x += y;
  }
  if (lane == 63) wtmp[wid] = x;
  __syncthreads(); // all sa reads done; wave totals visible
  double excl = x - run;
  for (int k = 0; k < wid; ++k) excl += wtmp[k];
#pragma unroll
  for (int j = 0; j < C; ++j) {
    const int i = base + j;
    if (i < N) sa[i] = excl + loc[j];
  }
  __syncthreads();
}

// ---------------- pass 2: mapping pipeline (stage2 fold + scans), one block ----------------
__global__ __launch_bounds__(256) void k_map(const double* __restrict__ stage2,
                                             int* __restrict__ src, PermArg perm) {
  __shared__ double sa[NCUTS_];
  __shared__ double wtmp[4];
  __shared__ float ex[W_ + 1];
  __shared__ unsigned char mm[W_];
  __shared__ int hist[W_ + 1];
  __shared__ int cuts[NCUTS_];
  __shared__ int pl[NSEG_], cum[NSEG_], ssrc[W_];
  const int t = threadIdx.x;

  // 0+1) fold stage2 (fixed k order) then prefix-scan; cast to f32 like reference cs
  for (int i = t; i < W_; i += 256) {
    double s = 0.0;
#pragma unroll
    for (int k = 0; k < 8; ++k) s += stage2[(size_t)k * W_ + i];
    sa[i] = s;
  }
  __syncthreads();
  scan_fast<W_>(sa, t, wtmp);
  for (int i = t; i <= W_; i += 256) ex[i] = (i == 0) ? 0.0f : (float)sa[i - 1];
  __syncthreads();

  // 2) windowed mean >= global mean mask
  const float gmean = ex[W_] / 45219840.0f; // n_bc*W = 65536*690
  for (int w = t; w < W_; w += 256) {
    int e = (w + 4 < W_) ? w + 4 : W_;
    float wsum = ex[e] - ex[w];
    float wmean = wsum / ((float)(e - w) * 65536.0f);
    mm[w] = (wmean >= gmean) ? 1 : 0;
  }
  for (int i = t; i <= W_; i += 256) hist[i] = 0;
  __syncthreads();

  // 3) counting-sort histogram of cut values
  for (int w = t; w < W_; w += 256) {
    bool cur = mm[w] != 0;
    bool prv = (w > 0) && (mm[w - 1] != 0);
    bool nxt = (w < W_ - 1) && (mm[w + 1] != 0);
    int sv = (cur && !prv) ? w : W_;
    int lv = (cur && !nxt) ? w : W_;
    atomicAdd(&hist[sv], 1);
    atomicAdd(&hist[lv], 1);
  }
  if (t == 0) { atomicAdd(&hist[0], 1); atomicAdd(&hist[W_], 1); }
  __syncthreads();

  // 4) inclusive scan of histogram
  for (int i = t; i <= W_; i += 256) sa[i] = (double)hist[i];
  __syncthreads();
  scan_fast<W_ + 1>(sa, t, wtmp);
  for (int i = t; i <= W_; i += 256) hist[i] = (int)(sa[i] + 0.5);
  __syncthreads();

  // 5) sorted cuts: cuts[k] = min v with hist_incl[v] > k
  for (int k = t; k < NCUTS_; k += 256) {
    int lo = 0, hi = W_;
    while (lo < hi) { int mid = (lo + hi) >> 1; if (hist[mid] > k) hi = mid; else lo = mid + 1; }
    cuts[k] = lo;
  }
  __syncthreads();

  // 6) permuted lengths + cumulative sum
  for (int k = t; k < NSEG_; k += 256) { int p = perm.p[k]; pl[k] = cuts[p + 1] - cuts[p]; }
  __syncthreads();
  for (int k = t; k < NSEG_; k += 256) sa[k] = (double)pl[k];
  __syncthreads();
  scan_fast<NSEG_>(sa, t, wtmp);
  for (int k = t; k < NSEG_; k += 256) cum[k] = (int)(sa[k] + 0.5);
  __syncthreads();

  // 7) fill src
  for (int k = t; k < NSEG_; k += 256) {
    int L = pl[k];
    if (L > 0) {
      int base = cum[k] - L;
      int s0 = cuts[perm.p[k]];
      for (int j = 0; j < L; ++j) ssrc[base + j] = s0 + j;
    }
  }
  __syncthreads();
  for (int p = t; p < W_; p += 256) src[p] = ssrc[p];
}

// ---------------- pass 3: direct gather — no LDS, no barriers ----------------
// Per-thread index quads are window-invariant: computed once into registers.
// Loop body: scattered dword loads (L1/L2-served, 5.5KB window) + NT float4 stores.
__global__ __launch_bounds__(256) void k_gather(const float* __restrict__ img,
                                                float* __restrict__ out,
                                                const int* __restrict__ src,
                                                int nwin, int rows) {
  const int t = threadIdx.x;
  const bool h2 = (t < GF4_ - 256); // t < 89 handles a second quad
  int i0[4], i1[4] = {0, 0, 0, 0};
#pragma unroll
  for (int e = 0; e < 4; ++e) {
    const int f = 4 * t + e;          // 0..1023; may cross the 690 row boundary
    const int s = src[(f < W_) ? f : f - W_];
    i0[e] = (f < W_) ? s : s + W_;
  }
  if (h2) {
#pragma unroll
    for (int e = 0; e < 4; ++e) {
      const int f = 4 * (t + 256) + e; // 1024..1379: always second row
      i1[e] = src[f - W_] + W_;
    }
  }
  for (int g = blockIdx.x; g < nwin; g += gridDim.x) {
    const float* in = img + (size_t)g * GFLT_;
    v4f_* o4 = (v4f_*)(out + (size_t)g * GFLT_); // 5520B*g: 16B aligned
    v4f_ a, b;
    a[0] = in[i0[0]]; a[1] = in[i0[1]]; a[2] = in[i0[2]]; a[3] = in[i0[3]];
    if (h2) { b[0] = in[i1[0]]; b[1] = in[i1[1]]; b[2] = in[i1[2]]; b[3] = in[i1[3]]; }
    __builtin_nontemporal_store(a, &o4[t]);
    if (h2) __builtin_nontemporal_store(b, &o4[t + 256]);
  }
  // tail row (rows odd) — not hit for rows=65536
  const int tail0 = nwin * 2;
  if (tail0 < rows && blockIdx.x == 0) {
    for (int r = tail0; r < rows; ++r) {
      const float* in = img + (size_t)r * W_;
      float* o = out + (size_t)r * W_;
      for (int p = t; p < W_; p += 256) o[p] = in[src[p]];
    }
  }
}

extern "C" void kernel_launch(void* const* d_in, const int* in_sizes, int n_in,
                              void* d_out, int out_size, void* d_ws, size_t ws_size,
                              hipStream_t stream) {
  const float* img = (const float*)d_in[0];
  float* out = (float*)d_out;
  const int rows = in_sizes[0] / W_; // 32*2048 = 65536

  // ws layout: stage2 f64[8*690] @0 (44160B) | src i32[690] @44160 | partial @47104
  char* ws = (char*)d_ws;
  double* stage2 = (double*)ws;
  int* src = (int*)(ws + 44160);
  double* partial = (double*)(ws + 47104);
  size_t avail = (ws_size > 47104) ? ws_size - 47104 : 0;
  int nblk = (int)std::min<size_t>(1792, avail / (W_ * sizeof(double)));
  if (nblk < 1) nblk = 1;
  const int ntiles = (rows + TR4_ - 1) / TR4_;
  const int nwin = rows / 2;

  PermArg pa;
  compute_perm(pa.p); // host, input-independent, deterministic

  k_colsum<<<nblk, 256, 0, stream>>>(img, partial, ntiles, rows);
  k_colreduce<<<88, 256, 0, stream>>>(partial, stage2, nblk);
  k_map<<<1, 256, 0, stream>>>(stage2, src, pa);
  k_gather<<<2048, 256, 0, stream>>>(img, out, src, nwin, rows);
}

// Round 17
// 110.680 us; speedup vs baseline: 1.0728x; 1.0728x over previous
//
#include <hip/hip_runtime.h>
#include <algorithm>
#include <cstdint>

// PRNG: partitionable threefry, 32-bit combine = o0 ^ o1  [VERIFIED R4: absmax=0]
// Final ledger: R8 gl2lds NEUTRAL; R9 fused-map -9us; R11 occupancy NEUTRAL;
// R12 T14 split NEUTRAL; R13/R14 reg-accum colsum -16us; R15 coalesced 2-stage
// colreduce -5.4us WIN (110.4 best); R16 direct-gather +8.3us (global scatter
// costs TA transactions per lane; LDS serves 64-lane scatter natively).
// R17: R15 restored verbatim — best-known configuration.

constexpr int W_ = 690;
constexpr int NSEG_ = 2 * W_ + 1;   // 1381 segments
constexpr int NCUTS_ = 2 * W_ + 2;  // 1382 cut points
constexpr int TR4_ = 4;             // rows per tile (colsum / gather)
constexpr int TFLT_ = TR4_ * W_;    // 2760 floats = 11040 B (16B-aligned tiles)
constexpr int TF4_ = TFLT_ / 4;     // 690 float4 per tile

typedef float v4f_ __attribute__((ext_vector_type(4)));
typedef int v4i_ __attribute__((ext_vector_type(4)));

struct PermArg { unsigned short p[NSEG_]; }; // 2762 B kernarg, values < 1381

// ---------------- host-side threefry2x32 (exact JAX semantics) ----------------
static inline uint32_t rotl32_(uint32_t x, int d) { return (x << d) | (x >> (32 - d)); }

static void tf2x32(uint32_t k0, uint32_t k1, uint32_t x0, uint32_t x1,
                   uint32_t& o0, uint32_t& o1) {
  const uint32_t ks2 = k0 ^ k1 ^ 0x1BD11BDAu;
  x0 += k0; x1 += k1;
  const int RA[4] = {13, 15, 26, 6}, RB[4] = {17, 29, 16, 24};
#define FOUR_(R) for (int i_ = 0; i_ < 4; ++i_) { x0 += x1; x1 = rotl32_(x1, R[i_]); x1 ^= x0; }
  FOUR_(RA) x0 += k1;  x1 += ks2 + 1u;
  FOUR_(RB) x0 += ks2; x1 += k0 + 2u;
  FOUR_(RA) x0 += k0;  x1 += k1 + 3u;
  FOUR_(RB) x0 += k1;  x1 += ks2 + 4u;
  FOUR_(RA) x0 += ks2; x1 += k0 + 5u;
#undef FOUR_
  o0 = x0; o1 = x1;
}

// perm = argsort(uniform(key(42), (1381,))) — pure function of constants.
static void compute_perm(unsigned short* perm) {
  uint32_t uk[NSEG_];
  for (int i = 0; i < NSEG_; ++i) {
    uint32_t o0, o1;
    tf2x32(0u, 42u, 0u, (uint32_t)i, o0, o1); // u64 count i: hi=0 -> x0, lo=i -> x1
    uk[i] = (o0 ^ o1) >> 9; // partitionable bit_width==32: bits1 ^ bits2
  }
  int idx[NSEG_];
  for (int i = 0; i < NSEG_; ++i) idx[i] = i;
  std::stable_sort(idx, idx + NSEG_, [&](int a, int b) { return uk[a] < uk[b]; });
  for (int k = 0; k < NSEG_; ++k) perm[k] = (unsigned short)idx[k];
}

// ---------------- pass 1: double-buffered reg-staged LDS colsum ----------------
__global__ __launch_bounds__(256) void k_colsum(const float* __restrict__ img,
                                                double* __restrict__ partial,
                                                int ntiles, int rows) {
  __shared__ float buf[2][TFLT_]; // 2 x 11040 B
  const int t = threadIdx.x;
  double a0 = 0.0, a1 = 0.0, a2 = 0.0;

  auto stage = [&](float* bp, int g) {
    const int nr = min(TR4_, rows - g * TR4_);
    if (nr == TR4_) {
      const v4f_* b4 = (const v4f_*)(img + (size_t)g * TFLT_); // 11040B*g: 16B aligned
      v4f_* t4 = (v4f_*)bp;
      for (int i = t; i < TF4_; i += 256) t4[i] = b4[i];
    } else {
      const int nflt = nr * W_;
      const float* b = img + (size_t)g * TFLT_;
      for (int i = t; i < nflt; i += 256) bp[i] = b[i];
    }
  };

  int g = blockIdx.x;
  int phase = 0;
  if (g < ntiles) stage(buf[0], g);
  for (; g < ntiles; g += gridDim.x) {
    __syncthreads(); // buf[phase] staged; prev accumulate of buf[phase^1] done
    const int gn = g + gridDim.x;
    if (gn < ntiles) stage(buf[phase ^ 1], gn); // prefetch next while we accumulate
    const int nr = min(TR4_, rows - g * TR4_);
    const float* bp = buf[phase];
    for (int r = 0; r < nr; ++r) {
      const float* row = bp + r * W_;
      a0 += (double)row[t];
      a1 += (double)row[t + 256];          // t+256 <= 511 < 690 always
      if (t + 512 < W_) a2 += (double)row[t + 512];
    }
    phase ^= 1;
  }
  double* o = partial + (size_t)blockIdx.x * W_;
  o[t] = a0;
  o[t + 256] = a1;
  if (t + 512 < W_) o[t + 512] = a2;
}

// ---------------- pass 1b: coalesced 2-stage reduction ----------------
// Grid 88 = 11 col-chunks x 8 b-chunks. Wave reads 64 CONSECUTIVE f64 per step
// (one 512B burst, each cache line fetched once, no cross-XCD duplication).
// Output stage2[8][690]; k_map folds the 8 rows (fixed order -> deterministic).
__global__ __launch_bounds__(256) void k_colreduce(const double* __restrict__ partial,
                                                   double* __restrict__ stage2, int nblk) {
  const int j = blockIdx.x >> 3;   // col chunk 0..10
  const int k = blockIdx.x & 7;    // b chunk 0..7
  const int t = threadIdx.x;
  const int c = j * 64 + (t & 63); // column
  const int wv = t >> 6;           // wave 0..3
  const bool ok = (c < W_);
  __shared__ double red[4][64];

  const int nsub = (nblk + 31) / 32;
  const int b0 = (k * 4 + wv) * nsub;
  const int b1 = min(b0 + nsub, nblk);
  double s0 = 0.0, s1 = 0.0, s2 = 0.0, s3 = 0.0;
  int b = b0;
  if (ok) {
    for (; b + 3 < b1; b += 4) { // 4 independent chains -> 4 loads in flight
      const double* p = partial + (size_t)b * W_ + c;
      s0 += p[0];
      s1 += p[(size_t)1 * W_];
      s2 += p[(size_t)2 * W_];
      s3 += p[(size_t)3 * W_];
    }
    for (; b < b1; ++b) s0 += partial[(size_t)b * W_ + c];
  }
  red[wv][t & 63] = (s0 + s1) + (s2 + s3);
  __syncthreads();
  if (wv == 0) {
    const int l = t & 63;
    const double tot = (red[0][l] + red[1][l]) + (red[2][l] + red[3][l]);
    if (ok) stage2[(size_t)k * W_ + c] = tot;
  }
}

// ---------------- hierarchical inclusive scan: 2 barriers, deterministic ----------------
template <int N>
__device__ inline void scan_fast(double* sa, int t, double* wtmp) {
  constexpr int C = (N + 255) / 256;
  double loc[C];
  const int base = t * C;
  double run = 0.0;
#pragma unroll
  for (int j = 0; j < C; ++j) {
    const int i = base + j;
    const double v = (i < N) ? sa[i] : 0.0;
    run += v;
    loc[j] = run;
  }
  const int lane = t & 63, wid = t >> 6;
  double x = run;
#pragma unroll
  for (int off = 1; off < 64; off <<= 1) {
    const double y = __shfl_up(x, off);
    if (lane >= off) x += y;
  }
  if (lane == 63) wtmp[wid] = x;
  __syncthreads(); // all sa reads done; wave totals visible
  double excl = x - run;
  for (int k = 0; k < wid; ++k) excl += wtmp[k];
#pragma unroll
  for (int j = 0; j < C; ++j) {
    const int i = base + j;
    if (i < N) sa[i] = excl + loc[j];
  }
  __syncthreads();
}

// ---------------- pass 2: mapping pipeline (stage2 fold + scans), one block ----------------
__global__ __launch_bounds__(256) void k_map(const double* __restrict__ stage2,
                                             int* __restrict__ src, PermArg perm) {
  __shared__ double sa[NCUTS_];
  __shared__ double wtmp[4];
  __shared__ float ex[W_ + 1];
  __shared__ unsigned char mm[W_];
  __shared__ int hist[W_ + 1];
  __shared__ int cuts[NCUTS_];
  __shared__ int pl[NSEG_], cum[NSEG_], ssrc[W_];
  const int t = threadIdx.x;

  // 0+1) fold stage2 (fixed k order) then prefix-scan; cast to f32 like reference cs
  for (int i = t; i < W_; i += 256) {
    double s = 0.0;
#pragma unroll
    for (int k = 0; k < 8; ++k) s += stage2[(size_t)k * W_ + i];
    sa[i] = s;
  }
  __syncthreads();
  scan_fast<W_>(sa, t, wtmp);
  for (int i = t; i <= W_; i += 256) ex[i] = (i == 0) ? 0.0f : (float)sa[i - 1];
  __syncthreads();

  // 2) windowed mean >= global mean mask
  const float gmean = ex[W_] / 45219840.0f; // n_bc*W = 65536*690
  for (int w = t; w < W_; w += 256) {
    int e = (w + 4 < W_) ? w + 4 : W_;
    float wsum = ex[e] - ex[w];
    float wmean = wsum / ((float)(e - w) * 65536.0f);
    mm[w] = (wmean >= gmean) ? 1 : 0;
  }
  for (int i = t; i <= W_; i += 256) hist[i] = 0;
  __syncthreads();

  // 3) counting-sort histogram of cut values
  for (int w = t; w < W_; w += 256) {
    bool cur = mm[w] != 0;
    bool prv = (w > 0) && (mm[w - 1] != 0);
    bool nxt = (w < W_ - 1) && (mm[w + 1] != 0);
    int sv = (cur && !prv) ? w : W_;
    int lv = (cur && !nxt) ? w : W_;
    atomicAdd(&hist[sv], 1);
    atomicAdd(&hist[lv], 1);
  }
  if (t == 0) { atomicAdd(&hist[0], 1); atomicAdd(&hist[W_], 1); }
  __syncthreads();

  // 4) inclusive scan of histogram
  for (int i = t; i <= W_; i += 256) sa[i] = (double)hist[i];
  __syncthreads();
  scan_fast<W_ + 1>(sa, t, wtmp);
  for (int i = t; i <= W_; i += 256) hist[i] = (int)(sa[i] + 0.5);
  __syncthreads();

  // 5) sorted cuts: cuts[k] = min v with hist_incl[v] > k
  for (int k = t; k < NCUTS_; k += 256) {
    int lo = 0, hi = W_;
    while (lo < hi) { int mid = (lo + hi) >> 1; if (hist[mid] > k) hi = mid; else lo = mid + 1; }
    cuts[k] = lo;
  }
  __syncthreads();

  // 6) permuted lengths + cumulative sum
  for (int k = t; k < NSEG_; k += 256) { int p = perm.p[k]; pl[k] = cuts[p + 1] - cuts[p]; }
  __syncthreads();
  for (int k = t; k < NSEG_; k += 256) sa[k] = (double)pl[k];
  __syncthreads();
  scan_fast<NSEG_>(sa, t, wtmp);
  for (int k = t; k < NSEG_; k += 256) cum[k] = (int)(sa[k] + 0.5);
  __syncthreads();

  // 7) fill src
  for (int k = t; k < NSEG_; k += 256) {
    int L = pl[k];
    if (L > 0) {
      int base = cum[k] - L;
      int s0 = cuts[perm.p[k]];
      for (int j = 0; j < L; ++j) ssrc[base + j] = s0 + j;
    }
  }
  __syncthreads();
  for (int p = t; p < W_; p += 256) src[p] = ssrc[p];
}

// ---------------- pass 3: double-buffered reg-staged LDS gather ----------------
__global__ __launch_bounds__(256) void k_gather(const float* __restrict__ img,
                                                float* __restrict__ out,
                                                const int* __restrict__ src,
                                                int ntile4, int rows) {
  __shared__ float buf[2][TFLT_];          // 2 x 11040 B
  __shared__ __align__(16) int ss[2 * W_]; // row-resolved source idx (1380)
  const int t = threadIdx.x;
  for (int i = t; i < W_; i += 256) {
    int s = src[i];
    ss[i] = s;
    ss[i + W_] = s + W_;
  }

  auto stage = [&](float* bp, int g) {
    const v4f_* in4 = (const v4f_*)(img + (size_t)g * TFLT_); // 16B aligned
    v4f_* t4 = (v4f_*)bp;
    for (int i = t; i < TF4_; i += 256) t4[i] = in4[i];
  };

  int g = blockIdx.x;
  int phase = 0;
  if (g < ntile4) stage(buf[0], g);
  for (; g < ntile4; g += gridDim.x) {
    __syncthreads(); // buf[phase] staged; prior reads of buf[phase^1] done
    const int gn = g + gridDim.x;
    if (gn < ntile4) stage(buf[phase ^ 1], gn); // prefetch next tile
    const float* bp = buf[phase];
    v4f_* o4 = (v4f_*)(out + (size_t)g * TFLT_);
    for (int q = t; q < TF4_; q += 256) {
      const int f = 4 * q;                       // quads never cross the 1380 boundary
      const int hb = (f >= 2 * W_) ? 2 * W_ : 0; // 2-row half base
      const float* hbuf = bp + hb;
      const v4i_ iv = *(const v4i_*)&ss[f - hb]; // one ds_read_b128
      v4f_ v;
      v[0] = hbuf[iv[0]];
      v[1] = hbuf[iv[1]];
      v[2] = hbuf[iv[2]];
      v[3] = hbuf[iv[3]];
      __builtin_nontemporal_store(v, &o4[q]);
    }
    phase ^= 1;
  }
  // tail rows (rows % 4), scalar — not hit for rows=65536
  const int tail0 = ntile4 * TR4_;
  if (tail0 < rows && blockIdx.x == 0) {
    __syncthreads();
    for (int r = tail0; r < rows; ++r) {
      const float* in = img + (size_t)r * W_;
      float* o = out + (size_t)r * W_;
      for (int p = t; p < W_; p += 256) o[p] = in[ss[p]];
    }
  }
}

extern "C" void kernel_launch(void* const* d_in, const int* in_sizes, int n_in,
                              void* d_out, int out_size, void* d_ws, size_t ws_size,
                              hipStream_t stream) {
  const float* img = (const float*)d_in[0];
  float* out = (float*)d_out;
  const int rows = in_sizes[0] / W_; // 32*2048 = 65536

  // ws layout: stage2 f64[8*690] @0 (44160B) | src i32[690] @44160 | partial @47104
  char* ws = (char*)d_ws;
  double* stage2 = (double*)ws;
  int* src = (int*)(ws + 44160);
  double* partial = (double*)(ws + 47104);
  size_t avail = (ws_size > 47104) ? ws_size - 47104 : 0;
  int nblk = (int)std::min<size_t>(1792, avail / (W_ * sizeof(double)));
  if (nblk < 1) nblk = 1;
  const int ntiles = (rows + TR4_ - 1) / TR4_;
  const int ntile4 = rows / TR4_;

  PermArg pa;
  compute_perm(pa.p); // host, input-independent, deterministic

  k_colsum<<<nblk, 256, 0, stream>>>(img, partial, ntiles, rows);
  k_colreduce<<<88, 256, 0, stream>>>(partial, stage2, nblk);
  k_map<<<1, 256, 0, stream>>>(stage2, src, pa);
  k_gather<<<1280, 256, 0, stream>>>(img, out, src, ntile4, rows);
}